// Round 6
// baseline (335.268 us; speedup 1.0000x reference)
//
#include <hip/hip_runtime.h>

#define NCLS 18
#define RPC 128                    // rows per chunk (per wave) in the rowwise kernel
#define CHF (RPC * NCLS)           // 2304 floats per array per chunk
#define CHF4 (CHF / 4)             // 576 float4
#define WPB 4
#define GRID_R 1024                // rowwise kernel: 4 blocks/CU (LDS-capped), same as R5
#define GRID_P 2048                // probe: 8 blocks/CU, zero LDS, full occupancy

// ---------- PROBE: pure m13-shape streaming reduce: sum(x*l) over all elems ----------
__global__ __launch_bounds__(256) void ce_dot_stream(
    const float4* __restrict__ X4,
    const float4* __restrict__ L4,
    float* __restrict__ pdot,
    int n4)
{
    const int tid = blockIdx.x * 256 + threadIdx.x;
    const int stride = gridDim.x * 256;

    float a0 = 0.0f, a1 = 0.0f;
    int i = tid;
    // 2-way manual unroll for MLP (4 independent loads in flight)
    for (; i + stride < n4; i += 2 * stride) {
        float4 x0 = X4[i],          l0 = L4[i];
        float4 x1 = X4[i + stride], l1 = L4[i + stride];
        a0 = fmaf(x0.x, l0.x, a0); a0 = fmaf(x0.y, l0.y, a0);
        a0 = fmaf(x0.z, l0.z, a0); a0 = fmaf(x0.w, l0.w, a0);
        a1 = fmaf(x1.x, l1.x, a1); a1 = fmaf(x1.y, l1.y, a1);
        a1 = fmaf(x1.z, l1.z, a1); a1 = fmaf(x1.w, l1.w, a1);
    }
    for (; i < n4; i += stride) {
        float4 x = X4[i], l = L4[i];
        a0 = fmaf(x.x, l.x, a0); a0 = fmaf(x.y, l.y, a0);
        a0 = fmaf(x.z, l.z, a0); a0 = fmaf(x.w, l.w, a0);
    }
    float acc = a0 + a1;

    #pragma unroll
    for (int off = 32; off > 0; off >>= 1) acc += __shfl_down(acc, off, 64);

    __shared__ float wsum[4];
    const int lane = threadIdx.x & 63, wid = threadIdx.x >> 6;
    if (lane == 0) wsum[wid] = acc;
    __syncthreads();
    if (threadIdx.x == 0) pdot[blockIdx.x] = wsum[0] + wsum[1] + wsum[2] + wsum[3];
}

// ---------- CONTROL: R5 structure computing sum_b sl_b * lse_b ----------
__global__ __launch_bounds__(256) void ce_sllse(
    const float4* __restrict__ X4,
    const float4* __restrict__ L4,
    float* __restrict__ psl,
    int B)
{
    __shared__ float s[WPB][CHF];   // 36,864 B -> 4 blocks/CU

    const int t    = threadIdx.x;
    const int lane = t & 63;
    const int wid  = t >> 6;
    const int gw   = blockIdx.x * WPB + wid;
    const int nw   = gridDim.x * WPB;
    const int nChunks = B / RPC;                 // 15,625 for B=2M

    float acc = 0.0f;

    for (int ch = gw; ch < nChunks; ch += nw) {
        const size_t g4 = (size_t)ch * CHF4;
        float4 v[9];

        // phase X
        #pragma unroll
        for (int j = 0; j < 9; ++j) v[j] = X4[g4 + (size_t)(j * 64 + lane)];
        #pragma unroll
        for (int j = 0; j < 9; ++j) *(float4*)&s[wid][(j * 64 + lane) * 4] = v[j];
        __builtin_amdgcn_wave_barrier();

        float se0 = 0.0f, se1 = 0.0f;
        {
            const float2* r0 = (const float2*)&s[wid][(2 * lane)     * NCLS];
            const float2* r1 = (const float2*)&s[wid][(2 * lane + 1) * NCLS];
            #pragma unroll
            for (int j = 0; j < 9; ++j) {
                float2 a = r0[j]; se0 += __expf(a.x) + __expf(a.y);
                float2 b = r1[j]; se1 += __expf(b.x) + __expf(b.y);
            }
        }
        __builtin_amdgcn_wave_barrier();

        // phase L (same buffer)
        #pragma unroll
        for (int j = 0; j < 9; ++j) v[j] = L4[g4 + (size_t)(j * 64 + lane)];
        #pragma unroll
        for (int j = 0; j < 9; ++j) *(float4*)&s[wid][(j * 64 + lane) * 4] = v[j];

        float lg0 = __logf(se0), lg1 = __logf(se1);

        __builtin_amdgcn_wave_barrier();

        float sl0 = 0.0f, sl1 = 0.0f;
        {
            const float2* r0 = (const float2*)&s[wid][(2 * lane)     * NCLS];
            const float2* r1 = (const float2*)&s[wid][(2 * lane + 1) * NCLS];
            #pragma unroll
            for (int j = 0; j < 9; ++j) {
                float2 a = r0[j]; sl0 += a.x + a.y;
                float2 b = r1[j]; sl1 += b.x + b.y;
            }
        }
        acc = fmaf(sl0, lg0, acc);
        acc = fmaf(sl1, lg1, acc);
        __builtin_amdgcn_wave_barrier();
    }

    // generic tail (empty for B=2M)
    const float2* X2 = (const float2*)X4;
    const float2* L2 = (const float2*)L4;
    for (int row = nChunks * RPC + gw * 64 + lane; row < B; row += nw * 64) {
        float se = 0.0f, sl = 0.0f;
        #pragma unroll
        for (int j = 0; j < 9; ++j) {
            float2 a = X2[(size_t)row * 9 + j]; se += __expf(a.x) + __expf(a.y);
            float2 b = L2[(size_t)row * 9 + j]; sl += b.x + b.y;
        }
        acc = fmaf(sl, __logf(se), acc);
    }

    #pragma unroll
    for (int off = 32; off > 0; off >>= 1) acc += __shfl_down(acc, off, 64);

    __shared__ float wsum[WPB];
    if (lane == 0) wsum[wid] = acc;
    __syncthreads();
    if (t == 0) psl[blockIdx.x] = wsum[0] + wsum[1] + wsum[2] + wsum[3];
}

// ---------- combine: out = (sum(psl) - sum(pdot)) / B ----------
__global__ __launch_bounds__(256) void ce_final(
    const float* __restrict__ pdot, int ndot,
    const float* __restrict__ psl, int nsl,
    float* __restrict__ out, float invB)
{
    float acc = 0.0f;
    for (int i = threadIdx.x; i < nsl; i += 256) acc += psl[i];
    for (int i = threadIdx.x; i < ndot; i += 256) acc -= pdot[i];

    #pragma unroll
    for (int off = 32; off > 0; off >>= 1) acc += __shfl_down(acc, off, 64);

    __shared__ float wsum[4];
    const int lane = threadIdx.x & 63, wid = threadIdx.x >> 6;
    if (lane == 0) wsum[wid] = acc;
    __syncthreads();
    if (threadIdx.x == 0)
        out[0] = (wsum[0] + wsum[1] + wsum[2] + wsum[3]) * invB;
}

extern "C" void kernel_launch(void* const* d_in, const int* in_sizes, int n_in,
                              void* d_out, int out_size, void* d_ws, size_t ws_size,
                              hipStream_t stream) {
    const float4* X4 = (const float4*)d_in[0];
    const float4* L4 = (const float4*)d_in[1];
    float* pdot = (float*)d_ws;                       // GRID_P floats
    float* psl  = (float*)d_ws + GRID_P;              // GRID_R floats (total 12 KB scratch)
    float* result = (float*)d_out;

    int B  = in_sizes[0] / NCLS;                      // 2,000,000
    int n4 = in_sizes[0] / 4;                         // 9,000,000 float4 per array

    ce_dot_stream<<<GRID_P, 256, 0, stream>>>(X4, L4, pdot, n4);
    ce_sllse<<<GRID_R, 256, 0, stream>>>(X4, L4, psl, B);
    ce_final<<<1, 256, 0, stream>>>(pdot, GRID_P, psl, GRID_R, result, 1.0f / (float)B);
}